// Round 2
// baseline (1228.716 us; speedup 1.0000x reference)
//
#include <hip/hip_runtime.h>
#include <math.h>

#define NN 50000
#define NE 400000
#define HD 512
#define EDIM 64
#define H2 1024
#define LDT 72  // padded LDS row stride (ushorts)

typedef short s16x8 __attribute__((ext_vector_type(8)));
typedef float f32x4 __attribute__((ext_vector_type(4)));

__device__ __forceinline__ unsigned short f2bf(float f) {
    union { float f; unsigned u; } v; v.f = f;
    unsigned r = v.u + 0x7fffu + ((v.u >> 16) & 1u);
    return (unsigned short)(r >> 16);
}
__device__ __forceinline__ float bf2f(unsigned short h) {
    union { unsigned u; float f; } v; v.u = ((unsigned)h) << 16;
    return v.f;
}
__device__ __forceinline__ float silu_f(float t) {
    return t / (1.f + __expf(-t));
}

// ---------------- workspace layout (bytes), total ~161.2 MB ----------------
constexpr size_t OFF_AGGR = 0;                        // f32 [NN][512] = 102,400,000; DEAD after k_combine
constexpr size_t OFF_H1   = 0;                        // bf16 [NN][1024] = 102,400,000 (aliases aggr)
constexpr size_t OFF_H    = 102400000;                // bf16 [NN][512] = 51,200,000
constexpr size_t OFF_WET  = 153600000;                // bf16 [512][64]
constexpr size_t OFF_W1T  = OFF_WET + 65536;          // bf16 [1024][512]
constexpr size_t OFF_W2T  = OFF_W1T + 1048576;        // bf16 [512][1024]
constexpr size_t OFF_CNT  = OFF_W2T + 1048576;        // int[50000]   (zeroed)
constexpr size_t OFF_B1S  = OFF_CNT + 200000;         // float[1024]  (zeroed)
constexpr size_t OFF_B1Q  = OFF_B1S + 4096;           // float[1024]  (zeroed)
constexpr size_t OFF_B2S  = OFF_B1Q + 4096;           // float[512]   (zeroed)
constexpr size_t OFF_B2Q  = OFF_B2S + 2048;           // float[512]   (zeroed)
constexpr size_t ZERO_BYTES = 200000 + 4096 + 4096 + 2048 + 2048;
constexpr size_t OFF_RP   = OFF_B2Q + 2048;           // int[50001]
constexpr size_t OFF_CUR  = OFF_RP + 200064;          // int[50000]
constexpr size_t OFF_SRCS = OFF_CUR + 200000;         // int[400000] src_sorted
constexpr size_t OFF_EIDX = OFF_SRCS + 1600000;       // int[400000] edge idx sorted
constexpr size_t OFF_DSTS = OFF_EIDX + 1600000;       // int[400000] dst_sorted
constexpr size_t OFF_SC1  = OFF_DSTS + 1600000;       // float[1024]
constexpr size_t OFF_SB1  = OFF_SC1 + 4096;           // float[1024]
constexpr size_t OFF_SC2  = OFF_SB1 + 4096;           // float[512]
constexpr size_t OFF_SB2  = OFF_SC2 + 2048;           // float[512]

// ---------------- weight transpose+convert to bf16 ----------------
__global__ __launch_bounds__(256) void k_convert(const float* __restrict__ We,
    const float* __restrict__ W1, const float* __restrict__ W2,
    unsigned short* __restrict__ wet, unsigned short* __restrict__ w1t,
    unsigned short* __restrict__ w2t) {
    int i = blockIdx.x * 256 + threadIdx.x;
    if (i < 32768) {                       // wet[n][k] = We[k][n]
        int n = i >> 6, k = i & 63;
        wet[i] = f2bf(We[k * HD + n]);
    } else if (i < 32768 + 524288) {       // w1t[n][k] = W1[k][n]
        int j = i - 32768;
        int n = j >> 9, k = j & 511;
        w1t[j] = f2bf(W1[k * H2 + n]);
    } else if (i < 32768 + 2 * 524288) {   // w2t[n][k] = W2[k][n]
        int j = i - (32768 + 524288);
        int n = j >> 10, k = j & 1023;
        w2t[j] = f2bf(W2[k * HD + n]);
    }
}

// ---------------- CSR build ----------------
__global__ __launch_bounds__(256) void k_hist(const int* __restrict__ dst, int* __restrict__ counts) {
    int e = blockIdx.x * 256 + threadIdx.x;
    if (e < NE) atomicAdd(&counts[dst[e]], 1);
}

__global__ __launch_bounds__(1024) void k_scan(const int* __restrict__ counts,
                                               int* __restrict__ row_ptr, int* __restrict__ cursor) {
    __shared__ int wsum[17];
    __shared__ int s_carry;
    int t = threadIdx.x;
    int lane = t & 63, wid = t >> 6;
    if (t == 0) s_carry = 0;
    __syncthreads();
    for (int base = 0; base < NN; base += 1024) {
        int i = base + t;
        int v = (i < NN) ? counts[i] : 0;
        int x = v;
        #pragma unroll
        for (int o = 1; o < 64; o <<= 1) {
            int y = __shfl_up(x, o, 64);
            if (lane >= o) x += y;
        }
        if (lane == 63) wsum[wid] = x;
        int carry = s_carry;
        __syncthreads();
        if (t == 0) {
            int run = 0;
            for (int w = 0; w < 16; ++w) { int tmp = wsum[w]; wsum[w] = run; run += tmp; }
            wsum[16] = run;
        }
        __syncthreads();
        int excl = x - v + wsum[wid] + carry;
        if (i < NN) { row_ptr[i] = excl; cursor[i] = excl; }
        __syncthreads();
        if (t == 0) s_carry = carry + wsum[16];
        __syncthreads();
    }
    if (t == 0) row_ptr[NN] = NE;
}

__global__ __launch_bounds__(256) void k_scatter(const int* __restrict__ src, const int* __restrict__ dst,
    int* __restrict__ cursor, int* __restrict__ src_s, int* __restrict__ eidx_s, int* __restrict__ dst_s) {
    int e = blockIdx.x * 256 + threadIdx.x;
    if (e < NE) {
        int d = dst[e];
        int p = atomicAdd(&cursor[d], 1);
        src_s[p] = src[e];
        eidx_s[p] = e;
        dst_s[p] = d;
    }
}

// ---------------- fused edge GEMM + segmented atomic aggregation ----------------
// For a tile of 128 dst-sorted edges: relu(ea[e]@We + x[src] + b_e), run-length
// merged over consecutive same-dst rows, atomicAdd into aggr[N][512] (fp32).
__global__ __launch_bounds__(256) void k_edge_fused(
    const float* __restrict__ ea, const unsigned short* __restrict__ wet,
    const float* __restrict__ x, const float* __restrict__ b_e,
    const int* __restrict__ src_s, const int* __restrict__ eidx_s, const int* __restrict__ dst_s,
    float* __restrict__ aggr) {
    __shared__ unsigned short As[128 * LDT];
    __shared__ unsigned short Bs[128 * LDT];
    int mblk = blockIdx.x;       // 3125 tiles of 128 sorted edges (exact)
    int nblk = blockIdx.y;       // 4 col tiles of 128
    int col0 = nblk * 128;
    int t = threadIdx.x;
    // stage A: 128 gathered edge rows x 64 fp32 -> bf16 LDS
    {
        int r = t >> 1, half = t & 1;
        int eidx = eidx_s[mblk * 128 + r];
        const float* gp = ea + (size_t)eidx * EDIM + half * 32;
        unsigned short* lp = As + r * LDT + half * 32;
        #pragma unroll
        for (int j = 0; j < 8; ++j) {
            float4 v = ((const float4*)gp)[j];
            lp[j * 4 + 0] = f2bf(v.x); lp[j * 4 + 1] = f2bf(v.y);
            lp[j * 4 + 2] = f2bf(v.z); lp[j * 4 + 3] = f2bf(v.w);
        }
    }
    // stage B: 128 rows of wet (n-major, k-contig)
    #pragma unroll
    for (int c = t; c < 1024; c += 256) {
        int r = c >> 3, k16 = c & 7;
        uint4 v = *(const uint4*)(wet + (size_t)(col0 + r) * EDIM + k16 * 8);
        *(uint4*)(Bs + r * LDT + k16 * 8) = v;
    }
    __syncthreads();
    int wid = t >> 6, lane = t & 63, l15 = lane & 15, quad = lane >> 4;
    f32x4 acc[2][8];
    #pragma unroll
    for (int i = 0; i < 2; ++i)
        #pragma unroll
        for (int j = 0; j < 8; ++j) acc[i][j] = (f32x4){0.f, 0.f, 0.f, 0.f};
    #pragma unroll
    for (int k0 = 0; k0 < 64; k0 += 32) {
        s16x8 af[2], bf[8];
        #pragma unroll
        for (int i = 0; i < 2; ++i)
            af[i] = *(const s16x8*)(As + (wid * 32 + i * 16 + l15) * LDT + k0 + quad * 8);
        #pragma unroll
        for (int j = 0; j < 8; ++j)
            bf[j] = *(const s16x8*)(Bs + (j * 16 + l15) * LDT + k0 + quad * 8);
        #pragma unroll
        for (int i = 0; i < 2; ++i)
            #pragma unroll
            for (int j = 0; j < 8; ++j)
                acc[i][j] = __builtin_amdgcn_mfma_f32_16x16x32_bf16(af[i], bf[j], acc[i][j], 0, 0, 0);
    }
    float bev[8];
    #pragma unroll
    for (int j = 0; j < 8; ++j) bev[j] = b_e[col0 + j * 16 + l15];
    #pragma unroll
    for (int i = 0; i < 2; ++i) {
        int rbase = mblk * 128 + wid * 32 + i * 16 + quad * 4;
        float run[8];
        #pragma unroll
        for (int j = 0; j < 8; ++j) run[j] = 0.f;
        int dprev = dst_s[rbase];
        #pragma unroll
        for (int r = 0; r < 4; ++r) {
            int row = rbase + r;
            int d = dst_s[row];
            int s = src_s[row];
            if (d != dprev) {
                float* ap = aggr + (size_t)dprev * HD + col0;
                #pragma unroll
                for (int j = 0; j < 8; ++j) { atomicAdd(ap + j * 16 + l15, run[j]); run[j] = 0.f; }
                dprev = d;
            }
            const float* xr = x + (size_t)s * HD + col0;
            #pragma unroll
            for (int j = 0; j < 8; ++j) {
                float v = acc[i][j][r] + xr[j * 16 + l15] + bev[j];
                run[j] += v > 0.f ? v : 0.f;
            }
        }
        float* ap = aggr + (size_t)dprev * HD + col0;
        #pragma unroll
        for (int j = 0; j < 8; ++j) atomicAdd(ap + j * 16 + l15, run[j]);
    }
}

// ---------------- h = bf16((1+eps)*x + aggr) ----------------
__global__ __launch_bounds__(256) void k_combine(const float* __restrict__ aggr,
    const float* __restrict__ x, const float* __restrict__ eps, unsigned short* __restrict__ h) {
    long i = ((long)blockIdx.x * 256 + threadIdx.x) * 4;
    if (i >= (long)NN * HD) return;
    float ep = 1.0f + eps[0];
    float4 a = *(const float4*)(aggr + i);
    float4 xv = *(const float4*)(x + i);
    unsigned short r0 = f2bf(ep * xv.x + a.x), r1 = f2bf(ep * xv.y + a.y);
    unsigned short r2 = f2bf(ep * xv.z + a.z), r3 = f2bf(ep * xv.w + a.w);
    uint2 p;
    p.x = (unsigned)r0 | ((unsigned)r1 << 16);
    p.y = (unsigned)r2 | ((unsigned)r3 << 16);
    *(uint2*)(h + i) = p;
}

// ---------------- bf16 GEMM with bias + fused BN column-stat epilogue ----------------
// C[M][Nn] = A[M][K] @ Bt[Nn][K]^T + bias. BF16OUT picks C dtype.
template <bool BF16OUT>
__global__ __launch_bounds__(256) void k_gemm_bn(
    const unsigned short* __restrict__ A, const unsigned short* __restrict__ Bt,
    const float* __restrict__ bias, void* __restrict__ Cv,
    float* __restrict__ bn_sum, float* __restrict__ bn_sumsq,
    int M, int K, int Nn) {
    __shared__ unsigned short As[128 * LDT];
    __shared__ unsigned short Bs[128 * LDT];
    __shared__ float csum[128], csumsq[128];
    int mblk = blockIdx.x, nblk = blockIdx.y;
    int t = threadIdx.x;
    int row0 = mblk * 128, col0 = nblk * 128;
    int wid = t >> 6, lane = t & 63, l15 = lane & 15, quad = lane >> 4;
    f32x4 acc[2][8];
    #pragma unroll
    for (int i = 0; i < 2; ++i)
        #pragma unroll
        for (int j = 0; j < 8; ++j) acc[i][j] = (f32x4){0.f, 0.f, 0.f, 0.f};

    for (int k0 = 0; k0 < K; k0 += 64) {
        __syncthreads();
        {
            int r = t >> 1, half = t & 1;
            int row = row0 + r;
            unsigned short* lp = As + r * LDT + half * 32;
            if (row < M) {
                const unsigned short* gp = A + (size_t)row * K + k0 + half * 32;
                #pragma unroll
                for (int jj = 0; jj < 4; ++jj) *(uint4*)(lp + jj * 8) = *(const uint4*)(gp + jj * 8);
            } else {
                uint4 z = {0u, 0u, 0u, 0u};
                #pragma unroll
                for (int jj = 0; jj < 4; ++jj) *(uint4*)(lp + jj * 8) = z;
            }
            const unsigned short* gb = Bt + (size_t)(col0 + r) * K + k0 + half * 32;
            unsigned short* lb = Bs + r * LDT + half * 32;
            #pragma unroll
            for (int jj = 0; jj < 4; ++jj) *(uint4*)(lb + jj * 8) = *(const uint4*)(gb + jj * 8);
        }
        __syncthreads();
        #pragma unroll
        for (int kk = 0; kk < 64; kk += 32) {
            s16x8 af[2], bf[8];
            #pragma unroll
            for (int i = 0; i < 2; ++i)
                af[i] = *(const s16x8*)(As + (wid * 32 + i * 16 + l15) * LDT + kk + quad * 8);
            #pragma unroll
            for (int j = 0; j < 8; ++j)
                bf[j] = *(const s16x8*)(Bs + (j * 16 + l15) * LDT + kk + quad * 8);
            #pragma unroll
            for (int i = 0; i < 2; ++i)
                #pragma unroll
                for (int j = 0; j < 8; ++j)
                    acc[i][j] = __builtin_amdgcn_mfma_f32_16x16x32_bf16(af[i], bf[j], acc[i][j], 0, 0, 0);
        }
    }
    if (t < 128) { csum[t] = 0.f; csumsq[t] = 0.f; }
    __syncthreads();
    int mrow0 = row0 + wid * 32;
    #pragma unroll
    for (int j = 0; j < 8; ++j) {
        int col = j * 16 + l15;
        float bv = bias[col0 + col];
        float ls = 0.f, lq = 0.f;
        #pragma unroll
        for (int i = 0; i < 2; ++i) {
            #pragma unroll
            for (int r = 0; r < 4; ++r) {
                int row = mrow0 + i * 16 + quad * 4 + r;
                if (row < M) {
                    float v = acc[i][j][r] + bv;
                    if (BF16OUT)
                        ((unsigned short*)Cv)[(size_t)row * Nn + col0 + col] = f2bf(v);
                    else
                        ((float*)Cv)[(size_t)row * Nn + col0 + col] = v;
                    ls += v; lq += v * v;
                }
            }
        }
        atomicAdd(&csum[col], ls);
        atomicAdd(&csumsq[col], lq);
    }
    __syncthreads();
    if (t < 128) {
        atomicAdd(bn_sum + col0 + t, csum[t]);
        atomicAdd(bn_sumsq + col0 + t, csumsq[t]);
    }
}

// ---------------- BN finalize ----------------
__global__ __launch_bounds__(256) void k_bn_final(const float* __restrict__ s,
    const float* __restrict__ q, const float* __restrict__ g, const float* __restrict__ beta,
    float* __restrict__ scale, float* __restrict__ sbias, int C, float invN) {
    int c = blockIdx.x * 256 + threadIdx.x;
    if (c < C) {
        float mu = s[c] * invN;
        float var = q[c] * invN - mu * mu;
        var = fmaxf(var, 0.f);
        float sc = g[c] * rsqrtf(var + 1e-5f);
        scale[c] = sc;
        sbias[c] = beta[c] - mu * sc;
    }
}

// ---------------- in-place a1 = bf16(silu(h1*scale+bias)) ----------------
__global__ __launch_bounds__(256) void k_act(unsigned short* __restrict__ h1,
    const float* __restrict__ sc, const float* __restrict__ sb, long total) {
    long i = ((long)blockIdx.x * 256 + threadIdx.x) * 4;
    if (i >= total) return;
    int c = (int)(i & (H2 - 1));
    uint2 p = *(const uint2*)(h1 + i);
    float4 s4 = *(const float4*)(sc + c);
    float4 b4 = *(const float4*)(sb + c);
    float t0 = bf2f((unsigned short)(p.x & 0xffffu)) * s4.x + b4.x;
    float t1 = bf2f((unsigned short)(p.x >> 16)) * s4.y + b4.y;
    float t2 = bf2f((unsigned short)(p.y & 0xffffu)) * s4.z + b4.z;
    float t3 = bf2f((unsigned short)(p.y >> 16)) * s4.w + b4.w;
    uint2 o;
    o.x = (unsigned)f2bf(silu_f(t0)) | ((unsigned)f2bf(silu_f(t1)) << 16);
    o.y = (unsigned)f2bf(silu_f(t2)) | ((unsigned)f2bf(silu_f(t3)) << 16);
    *(uint2*)(h1 + i) = o;
}

// ---------------- in-place out = silu(out*scale+bias) fp32 ----------------
__global__ __launch_bounds__(256) void k_out(float* __restrict__ out,
    const float* __restrict__ sc, const float* __restrict__ sb, long total) {
    long i = ((long)blockIdx.x * 256 + threadIdx.x) * 4;
    if (i >= total) return;
    int c = (int)(i & (HD - 1));
    float4 v = *(const float4*)(out + i);
    float4 s4 = *(const float4*)(sc + c);
    float4 b4 = *(const float4*)(sb + c);
    float4 o;
    o.x = silu_f(v.x * s4.x + b4.x);
    o.y = silu_f(v.y * s4.y + b4.y);
    o.z = silu_f(v.z * s4.z + b4.z);
    o.w = silu_f(v.w * s4.w + b4.w);
    *(float4*)(out + i) = o;
}

extern "C" void kernel_launch(void* const* d_in, const int* in_sizes, int n_in,
                              void* d_out, int out_size, void* d_ws, size_t ws_size,
                              hipStream_t stream) {
    const float* x      = (const float*)d_in[0];
    const float* ea     = (const float*)d_in[1];
    const int*   ei     = (const int*)d_in[2];     // [2][E]: src then dst
    const float* W_e    = (const float*)d_in[3];
    const float* b_e    = (const float*)d_in[4];
    const float* W1     = (const float*)d_in[5];
    const float* b1     = (const float*)d_in[6];
    const float* g1     = (const float*)d_in[7];
    const float* beta1  = (const float*)d_in[8];
    const float* W2     = (const float*)d_in[9];
    const float* b2     = (const float*)d_in[10];
    const float* g2     = (const float*)d_in[11];
    const float* beta2  = (const float*)d_in[12];
    const float* eps    = (const float*)d_in[13];
    float* out = (float*)d_out;
    char* ws = (char*)d_ws;
    // NOTE: no ws_size guard — round-1's silent early return hid the failure.
    // Footprint is ~161.2 MB; if ws is smaller we fault loudly instead.

    float*          aggr = (float*)(ws + OFF_AGGR);
    unsigned short* h1   = (unsigned short*)(ws + OFF_H1);   // aliases aggr (dead then)
    unsigned short* h    = (unsigned short*)(ws + OFF_H);
    unsigned short* wet  = (unsigned short*)(ws + OFF_WET);
    unsigned short* w1t  = (unsigned short*)(ws + OFF_W1T);
    unsigned short* w2t  = (unsigned short*)(ws + OFF_W2T);
    int* counts  = (int*)(ws + OFF_CNT);
    float* b1s   = (float*)(ws + OFF_B1S);
    float* b1q   = (float*)(ws + OFF_B1Q);
    float* b2s   = (float*)(ws + OFF_B2S);
    float* b2q   = (float*)(ws + OFF_B2Q);
    int* row_ptr = (int*)(ws + OFF_RP);
    int* cursor  = (int*)(ws + OFF_CUR);
    int* src_s   = (int*)(ws + OFF_SRCS);
    int* eidx_s  = (int*)(ws + OFF_EIDX);
    int* dst_s   = (int*)(ws + OFF_DSTS);
    float* sc1   = (float*)(ws + OFF_SC1);
    float* sb1   = (float*)(ws + OFF_SB1);
    float* sc2   = (float*)(ws + OFF_SC2);
    float* sb2   = (float*)(ws + OFF_SB2);

    hipMemsetAsync(aggr, 0, 102400000, stream);
    hipMemsetAsync(ws + OFF_CNT, 0, ZERO_BYTES, stream);
    k_convert<<<4224, 256, 0, stream>>>(W_e, W1, W2, wet, w1t, w2t);
    k_hist<<<(NE + 255) / 256, 256, 0, stream>>>(ei + NE, counts);
    k_scan<<<1, 1024, 0, stream>>>(counts, row_ptr, cursor);
    k_scatter<<<(NE + 255) / 256, 256, 0, stream>>>(ei, ei + NE, cursor, src_s, eidx_s, dst_s);
    k_edge_fused<<<dim3(NE / 128, 4), 256, 0, stream>>>(ea, wet, x, b_e, src_s, eidx_s, dst_s, aggr);
    k_combine<<<(int)(((long)NN * HD / 4 + 255) / 256), 256, 0, stream>>>(aggr, x, eps, h);
    k_gemm_bn<true><<<dim3((NN + 127) / 128, H2 / 128), 256, 0, stream>>>(h, w1t, b1, h1, b1s, b1q, NN, HD, H2);
    k_bn_final<<<4, 256, 0, stream>>>(b1s, b1q, g1, beta1, sc1, sb1, H2, 1.f / NN);
    k_act<<<(int)(((long)NN * H2 / 4 + 255) / 256), 256, 0, stream>>>(h1, sc1, sb1, (long)NN * H2);
    k_gemm_bn<false><<<dim3((NN + 127) / 128, HD / 128), 256, 0, stream>>>(h1, w2t, b2, out, b2s, b2q, NN, H2, HD);
    k_bn_final<<<2, 256, 0, stream>>>(b2s, b2q, g2, beta2, sc2, sb2, HD, 1.f / NN);
    k_out<<<(int)(((long)NN * HD / 4 + 255) / 256), 256, 0, stream>>>(out, sc2, sb2, (long)NN * HD);
}

// Round 3
// 1166.469 us; speedup vs baseline: 1.0534x; 1.0534x over previous
//
#include <hip/hip_runtime.h>
#include <math.h>

#define NN 50000
#define NE 400000
#define HD 512
#define EDIM 64
#define H2 1024
#define LDT 72           // padded LDS row stride (ushorts)
#define CAP_SLOT 1200000 // padded edge-slot capacity (>= NE + 16*NN worst pad)
#define CAP_TILE 75000   // CAP_SLOT/16
#define NBLK_SCAN 98     // ceil(NN/512)

typedef short s16x8 __attribute__((ext_vector_type(8)));
typedef float f32x4 __attribute__((ext_vector_type(4)));

__device__ __forceinline__ unsigned short f2bf(float f) {
    union { float f; unsigned u; } v; v.f = f;
    unsigned r = v.u + 0x7fffu + ((v.u >> 16) & 1u);
    return (unsigned short)(r >> 16);
}
__device__ __forceinline__ float bf2f(unsigned short h) {
    union { unsigned u; float f; } v; v.u = ((unsigned)h) << 16;
    return v.f;
}
__device__ __forceinline__ float silu_f(float t) {
    return t / (1.f + __expf(-t));
}

// ---------------- workspace layout (bytes), total ~166.3 MB ----------------
constexpr size_t OFF_AGGR = 0;                        // f32 [NN][512]; DEAD after k_combine
constexpr size_t OFF_H1   = 0;                        // bf16 [NN][1024] (aliases aggr)
constexpr size_t OFF_H    = 102400000;                // bf16 [NN][512]
constexpr size_t OFF_WET  = 153600000;                // bf16 [512][64]
constexpr size_t OFF_W1T  = OFF_WET + 65536;          // bf16 [1024][512]
constexpr size_t OFF_W2T  = OFF_W1T + 1048576;        // bf16 [512][1024]
constexpr size_t OFF_CNT  = OFF_W2T + 1048576;        // int[50000]   (zeroed)
constexpr size_t OFF_B1S  = OFF_CNT + 200000;         // float[1024]  (zeroed)
constexpr size_t OFF_B1Q  = OFF_B1S + 4096;           // float[1024]  (zeroed)
constexpr size_t OFF_B2S  = OFF_B1Q + 4096;           // float[512]   (zeroed)
constexpr size_t OFF_B2Q  = OFF_B2S + 2048;           // float[512]   (zeroed)
constexpr size_t ZERO_BYTES = 200000 + 4096 + 4096 + 2048 + 2048;
constexpr size_t OFF_TEX  = OFF_B2Q + 2048;           // int[50000] tile_excl
constexpr size_t OFF_BSUM = OFF_TEX + 200000;         // int[128]
constexpr size_t OFF_BOFF = OFF_BSUM + 512;           // int[128]
constexpr size_t OFF_T    = OFF_BOFF + 512;           // int[16]
constexpr size_t OFF_CUR  = OFF_T + 64;               // int[50000]
constexpr size_t OFF_NOT  = OFF_CUR + 200000;         // int[75008] node_of_tile
constexpr size_t OFF_SRCP = OFF_NOT + 300032;         // int[CAP_SLOT] (memset 0xFF)
constexpr size_t OFF_EIXP = OFF_SRCP + 4800000;       // int[CAP_SLOT]
constexpr size_t OFF_SC1  = OFF_EIXP + 4800000;       // float[1024]
constexpr size_t OFF_SB1  = OFF_SC1 + 4096;           // float[1024]
constexpr size_t OFF_SC2  = OFF_SB1 + 4096;           // float[512]
constexpr size_t OFF_SB2  = OFF_SC2 + 2048;           // float[512]

// ---------------- weight transpose+convert to bf16 ----------------
__global__ __launch_bounds__(256) void k_convert(const float* __restrict__ We,
    const float* __restrict__ W1, const float* __restrict__ W2,
    unsigned short* __restrict__ wet, unsigned short* __restrict__ w1t,
    unsigned short* __restrict__ w2t) {
    int i = blockIdx.x * 256 + threadIdx.x;
    if (i < 32768) {
        int n = i >> 6, k = i & 63;
        wet[i] = f2bf(We[k * HD + n]);
    } else if (i < 32768 + 524288) {
        int j = i - 32768;
        int n = j >> 9, k = j & 511;
        w1t[j] = f2bf(W1[k * H2 + n]);
    } else if (i < 32768 + 2 * 524288) {
        int j = i - (32768 + 524288);
        int n = j >> 10, k = j & 1023;
        w2t[j] = f2bf(W2[k * HD + n]);
    }
}

// ---------------- histogram of dst ----------------
__global__ __launch_bounds__(256) void k_hist(const int* __restrict__ dst, int* __restrict__ counts) {
    int e = blockIdx.x * 256 + threadIdx.x;
    if (e < NE) atomicAdd(&counts[dst[e]], 1);
}

// ---------------- 3-phase scan of padded tile counts ----------------
__global__ __launch_bounds__(512) void k_scan1(const int* __restrict__ counts,
    int* __restrict__ tile_excl, int* __restrict__ bsum) {
    __shared__ int wsums[8];
    int b = blockIdx.x, t = threadIdx.x;
    int i = b * 512 + t;
    int v = (i < NN) ? ((counts[i] + 15) >> 4) : 0;   // tile count for node
    int lane = t & 63, wid = t >> 6;
    int x = v;
    #pragma unroll
    for (int o = 1; o < 64; o <<= 1) {
        int y = __shfl_up(x, o, 64);
        if (lane >= o) x += y;
    }
    if (lane == 63) wsums[wid] = x;
    __syncthreads();
    if (t == 0) {
        int run = 0;
        for (int w = 0; w < 8; ++w) { int tmp = wsums[w]; wsums[w] = run; run += tmp; }
    }
    __syncthreads();
    int excl = x - v + wsums[wid];
    if (i < NN) tile_excl[i] = excl;
    if (t == 511) bsum[b] = excl + v;
}

__global__ void k_scan2(const int* __restrict__ bsum, int* __restrict__ boff, int* __restrict__ Tout) {
    if (threadIdx.x == 0) {
        int run = 0;
        for (int b = 0; b < NBLK_SCAN; ++b) { boff[b] = run; run += bsum[b]; }
        Tout[0] = run;
    }
}

__global__ __launch_bounds__(512) void k_scan3(const int* __restrict__ counts,
    const int* __restrict__ tile_excl, const int* __restrict__ boff,
    int* __restrict__ cursor, int* __restrict__ node_of_tile) {
    int b = blockIdx.x, t = threadIdx.x;
    int i = b * 512 + t;
    if (i >= NN) return;
    int tc = (counts[i] + 15) >> 4;
    int ts = tile_excl[i] + boff[b];
    cursor[i] = ts * 16;
    unsigned tag = (unsigned)i | (tc > 1 ? 0x80000000u : 0u);
    for (int k = 0; k < tc; ++k) node_of_tile[ts + k] = (int)tag;
}

// ---------------- scatter edges into padded (ELL) slots ----------------
__global__ __launch_bounds__(256) void k_scatter(const int* __restrict__ src, const int* __restrict__ dst,
    int* __restrict__ cursor, int* __restrict__ srcp, int* __restrict__ eidxp) {
    int e = blockIdx.x * 256 + threadIdx.x;
    if (e < NE) {
        int d = dst[e];
        int p = atomicAdd(&cursor[d], 1);
        srcp[p] = src[e];
        eidxp[p] = e;
    }
}

// ---------------- fused edge GEMM + node-aligned reduce, NO atomics for deg<=16 ----------------
// block = 8 tiles (128 padded edge slots) x 512 cols. 8 waves: (row-half, col-block).
__global__ __launch_bounds__(512) void k_edge(
    const float* __restrict__ ea, const unsigned short* __restrict__ wet,
    const float* __restrict__ x, const float* __restrict__ b_e,
    const int* __restrict__ srcp, const int* __restrict__ eidxp,
    const int* __restrict__ node_of_tile, const int* __restrict__ Tptr,
    float* __restrict__ aggr) {
    int tile0 = blockIdx.x * 8;
    int T = Tptr[0];
    if (tile0 >= T) return;
    __shared__ unsigned short As[128 * LDT];   // 18.4 KB
    __shared__ unsigned short Bs[512 * LDT];   // 73.7 KB
    int t = threadIdx.x;
    int slot0 = tile0 * 16;
    // stage A: 128 gathered ea rows -> bf16 (zeros for pad slots)
    {
        int r = t >> 2, qq = t & 3;
        int s = srcp[slot0 + r];
        unsigned short* lp = As + r * LDT + qq * 16;
        if (s >= 0) {
            int eix = eidxp[slot0 + r];
            const float* gp = ea + (size_t)eix * EDIM + qq * 16;
            #pragma unroll
            for (int j = 0; j < 4; ++j) {
                float4 vv = ((const float4*)gp)[j];
                lp[j * 4 + 0] = f2bf(vv.x); lp[j * 4 + 1] = f2bf(vv.y);
                lp[j * 4 + 2] = f2bf(vv.z); lp[j * 4 + 3] = f2bf(vv.w);
            }
        } else {
            uint4 z = {0u, 0u, 0u, 0u};
            *(uint4*)lp = z; *(uint4*)(lp + 8) = z;
        }
    }
    // stage B: all 512 wet rows (k-contig 128B each)
    {
        const unsigned short* gb = wet + (size_t)t * EDIM;
        unsigned short* lb = Bs + t * LDT;
        #pragma unroll
        for (int jj = 0; jj < 8; ++jj) *(uint4*)(lb + jj * 8) = *(const uint4*)(gb + jj * 8);
    }
    __syncthreads();
    int wave = t >> 6, lane = t & 63, l15 = lane & 15, quad = lane >> 4;
    int rhalf = (wave >> 2) * 64;
    int cblk = (wave & 3) * 128;
    f32x4 acc[4][8];
    #pragma unroll
    for (int i = 0; i < 4; ++i)
        #pragma unroll
        for (int j = 0; j < 8; ++j) acc[i][j] = (f32x4){0.f, 0.f, 0.f, 0.f};
    #pragma unroll
    for (int k0 = 0; k0 < 64; k0 += 32) {
        s16x8 af[4], bfr[8];
        #pragma unroll
        for (int i = 0; i < 4; ++i)
            af[i] = *(const s16x8*)(As + (rhalf + i * 16 + l15) * LDT + k0 + quad * 8);
        #pragma unroll
        for (int j = 0; j < 8; ++j)
            bfr[j] = *(const s16x8*)(Bs + (cblk + j * 16 + l15) * LDT + k0 + quad * 8);
        #pragma unroll
        for (int i = 0; i < 4; ++i)
            #pragma unroll
            for (int j = 0; j < 8; ++j)
                acc[i][j] = __builtin_amdgcn_mfma_f32_16x16x32_bf16(af[i], bfr[j], acc[i][j], 0, 0, 0);
    }
    float bev[8];
    #pragma unroll
    for (int j = 0; j < 8; ++j) bev[j] = b_e[cblk + j * 16 + l15];
    #pragma unroll
    for (int i = 0; i < 4; ++i) {
        int tl = (rhalf >> 4) + i;          // local tile 0..7
        int tile = tile0 + tl;
        if (tile >= T) continue;
        unsigned meta = (unsigned)node_of_tile[tile];
        int v = (int)(meta & 0x7fffffffu);
        int srow = slot0 + tl * 16 + quad * 4;
        float sum8[8];
        #pragma unroll
        for (int j = 0; j < 8; ++j) sum8[j] = 0.f;
        #pragma unroll
        for (int r = 0; r < 4; ++r) {
            int s = srcp[srow + r];
            if (s >= 0) {
                const float* xr = x + (size_t)s * HD + cblk;
                #pragma unroll
                for (int j = 0; j < 8; ++j) {
                    float vv = acc[i][j][r] + xr[j * 16 + l15] + bev[j];
                    sum8[j] += vv > 0.f ? vv : 0.f;
                }
            }
        }
        #pragma unroll
        for (int j = 0; j < 8; ++j) {
            sum8[j] += __shfl_xor(sum8[j], 16, 64);
            sum8[j] += __shfl_xor(sum8[j], 32, 64);
        }
        if (quad == 0) {
            float* ap = aggr + (size_t)v * HD + cblk;
            if (meta & 0x80000000u) {
                #pragma unroll
                for (int j = 0; j < 8; ++j) atomicAdd(ap + j * 16 + l15, sum8[j]);
            } else {
                #pragma unroll
                for (int j = 0; j < 8; ++j) ap[j * 16 + l15] = sum8[j];
            }
        }
    }
}

// ---------------- h = bf16((1+eps)*x + aggr) ----------------
__global__ __launch_bounds__(256) void k_combine(const float* __restrict__ aggr,
    const float* __restrict__ x, const float* __restrict__ eps, unsigned short* __restrict__ h) {
    long i = ((long)blockIdx.x * 256 + threadIdx.x) * 4;
    if (i >= (long)NN * HD) return;
    float ep = 1.0f + eps[0];
    float4 a = *(const float4*)(aggr + i);
    float4 xv = *(const float4*)(x + i);
    uint2 p;
    p.x = (unsigned)f2bf(ep * xv.x + a.x) | ((unsigned)f2bf(ep * xv.y + a.y) << 16);
    p.y = (unsigned)f2bf(ep * xv.z + a.z) | ((unsigned)f2bf(ep * xv.w + a.w) << 16);
    *(uint2*)(h + i) = p;
}

// ---------------- bf16 GEMM + bias + BN column stats; optional fused SiLU-BN on A ----------------
template <bool BF16OUT, bool SILU_A>
__global__ __launch_bounds__(256) void k_gemm_bn(
    const unsigned short* __restrict__ A, const unsigned short* __restrict__ Bt,
    const float* __restrict__ bias, void* __restrict__ Cv,
    float* __restrict__ bn_sum, float* __restrict__ bn_sumsq,
    const float* __restrict__ a_sc, const float* __restrict__ a_sb,
    int M, int K, int Nn) {
    __shared__ unsigned short As[128 * LDT];
    __shared__ unsigned short Bs[128 * LDT];
    __shared__ float csum[128], csumsq[128];
    int mblk = blockIdx.x, nblk = blockIdx.y;
    int t = threadIdx.x;
    int row0 = mblk * 128, col0 = nblk * 128;
    int wid = t >> 6, lane = t & 63, l15 = lane & 15, quad = lane >> 4;
    f32x4 acc[2][8];
    #pragma unroll
    for (int i = 0; i < 2; ++i)
        #pragma unroll
        for (int j = 0; j < 8; ++j) acc[i][j] = (f32x4){0.f, 0.f, 0.f, 0.f};

    for (int k0 = 0; k0 < K; k0 += 64) {
        __syncthreads();
        {
            int r = t >> 1, half = t & 1;
            int row = row0 + r;
            int kb = k0 + half * 32;
            unsigned short* lp = As + r * LDT + half * 32;
            if (row < M) {
                const unsigned short* gp = A + (size_t)row * K + kb;
                if (SILU_A) {
                    #pragma unroll
                    for (int jj = 0; jj < 4; ++jj) {
                        uint4 u = *(const uint4*)(gp + jj * 8);
                        float4 sA = *(const float4*)(a_sc + kb + jj * 8);
                        float4 sB = *(const float4*)(a_sc + kb + jj * 8 + 4);
                        float4 bA = *(const float4*)(a_sb + kb + jj * 8);
                        float4 bB = *(const float4*)(a_sb + kb + jj * 8 + 4);
                        unsigned short o[8];
                        o[0] = f2bf(silu_f(bf2f((unsigned short)(u.x & 0xffffu)) * sA.x + bA.x));
                        o[1] = f2bf(silu_f(bf2f((unsigned short)(u.x >> 16)) * sA.y + bA.y));
                        o[2] = f2bf(silu_f(bf2f((unsigned short)(u.y & 0xffffu)) * sA.z + bA.z));
                        o[3] = f2bf(silu_f(bf2f((unsigned short)(u.y >> 16)) * sA.w + bA.w));
                        o[4] = f2bf(silu_f(bf2f((unsigned short)(u.z & 0xffffu)) * sB.x + bB.x));
                        o[5] = f2bf(silu_f(bf2f((unsigned short)(u.z >> 16)) * sB.y + bB.y));
                        o[6] = f2bf(silu_f(bf2f((unsigned short)(u.w & 0xffffu)) * sB.z + bB.z));
                        o[7] = f2bf(silu_f(bf2f((unsigned short)(u.w >> 16)) * sB.w + bB.w));
                        #pragma unroll
                        for (int m = 0; m < 8; ++m) lp[jj * 8 + m] = o[m];
                    }
                } else {
                    #pragma unroll
                    for (int jj = 0; jj < 4; ++jj) *(uint4*)(lp + jj * 8) = *(const uint4*)(gp + jj * 8);
                }
            } else {
                uint4 z = {0u, 0u, 0u, 0u};
                #pragma unroll
                for (int jj = 0; jj < 4; ++jj) *(uint4*)(lp + jj * 8) = z;
            }
            const unsigned short* gb = Bt + (size_t)(col0 + r) * K + kb;
            unsigned short* lb = Bs + r * LDT + half * 32;
            #pragma unroll
            for (int jj = 0; jj < 4; ++jj) *(uint4*)(lb + jj * 8) = *(const uint4*)(gb + jj * 8);
        }
        __syncthreads();
        #pragma unroll
        for (int kk = 0; kk < 64; kk += 32) {
            s16x8 af[2], bfr[8];
            #pragma unroll
            for (int i = 0; i < 2; ++i)
                af[i] = *(const s16x8*)(As + (wid * 32 + i * 16 + l15) * LDT + kk + quad * 8);
            #pragma unroll
            for (int j = 0; j < 8; ++j)
                bfr[j] = *(const s16x8*)(Bs + (j * 16 + l15) * LDT + kk + quad * 8);
            #pragma unroll
            for (int i = 0; i < 2; ++i)
                #pragma unroll
                for (int j = 0; j < 8; ++j)
                    acc[i][j] = __builtin_amdgcn_mfma_f32_16x16x32_bf16(af[i], bfr[j], acc[i][j], 0, 0, 0);
        }
    }
    if (t < 128) { csum[t] = 0.f; csumsq[t] = 0.f; }
    __syncthreads();
    int mrow0 = row0 + wid * 32;
    #pragma unroll
    for (int j = 0; j < 8; ++j) {
        int col = j * 16 + l15;
        float bv = bias[col0 + col];
        float ls = 0.f, lq = 0.f;
        #pragma unroll
        for (int i = 0; i < 2; ++i) {
            #pragma unroll
            for (int r = 0; r < 4; ++r) {
                int row = mrow0 + i * 16 + quad * 4 + r;
                if (row < M) {
                    float v = acc[i][j][r] + bv;
                    if (BF16OUT)
                        ((unsigned short*)Cv)[(size_t)row * Nn + col0 + col] = f2bf(v);
                    else
                        ((float*)Cv)[(size_t)row * Nn + col0 + col] = v;
                    ls += v; lq += v * v;
                }
            }
        }
        atomicAdd(&csum[col], ls);
        atomicAdd(&csumsq[col], lq);
    }
    __syncthreads();
    if (t < 128) {
        atomicAdd(bn_sum + col0 + t, csum[t]);
        atomicAdd(bn_sumsq + col0 + t, csumsq[t]);
    }
}

// ---------------- BN finalize ----------------
__global__ __launch_bounds__(256) void k_bn_final(const float* __restrict__ s,
    const float* __restrict__ q, const float* __restrict__ g, const float* __restrict__ beta,
    float* __restrict__ scale, float* __restrict__ sbias, int C, float invN) {
    int c = blockIdx.x * 256 + threadIdx.x;
    if (c < C) {
        float mu = s[c] * invN;
        float var = q[c] * invN - mu * mu;
        var = fmaxf(var, 0.f);
        float sc = g[c] * rsqrtf(var + 1e-5f);
        scale[c] = sc;
        sbias[c] = beta[c] - mu * sc;
    }
}

// ---------------- in-place out = silu(out*scale+bias) fp32 ----------------
__global__ __launch_bounds__(256) void k_out(float* __restrict__ out,
    const float* __restrict__ sc, const float* __restrict__ sb, long total) {
    long i = ((long)blockIdx.x * 256 + threadIdx.x) * 4;
    if (i >= total) return;
    int c = (int)(i & (HD - 1));
    float4 v = *(const float4*)(out + i);
    float4 s4 = *(const float4*)(sc + c);
    float4 b4 = *(const float4*)(sb + c);
    float4 o;
    o.x = silu_f(v.x * s4.x + b4.x);
    o.y = silu_f(v.y * s4.y + b4.y);
    o.z = silu_f(v.z * s4.z + b4.z);
    o.w = silu_f(v.w * s4.w + b4.w);
    *(float4*)(out + i) = o;
}

extern "C" void kernel_launch(void* const* d_in, const int* in_sizes, int n_in,
                              void* d_out, int out_size, void* d_ws, size_t ws_size,
                              hipStream_t stream) {
    const float* x      = (const float*)d_in[0];
    const float* ea     = (const float*)d_in[1];
    const int*   ei     = (const int*)d_in[2];     // [2][E]: src then dst
    const float* W_e    = (const float*)d_in[3];
    const float* b_e    = (const float*)d_in[4];
    const float* W1     = (const float*)d_in[5];
    const float* b1     = (const float*)d_in[6];
    const float* g1     = (const float*)d_in[7];
    const float* beta1  = (const float*)d_in[8];
    const float* W2     = (const float*)d_in[9];
    const float* b2     = (const float*)d_in[10];
    const float* g2     = (const float*)d_in[11];
    const float* beta2  = (const float*)d_in[12];
    const float* eps    = (const float*)d_in[13];
    float* out = (float*)d_out;
    char* ws = (char*)d_ws;

    float*          aggr = (float*)(ws + OFF_AGGR);
    unsigned short* h1   = (unsigned short*)(ws + OFF_H1);   // aliases aggr (dead then)
    unsigned short* h    = (unsigned short*)(ws + OFF_H);
    unsigned short* wet  = (unsigned short*)(ws + OFF_WET);
    unsigned short* w1t  = (unsigned short*)(ws + OFF_W1T);
    unsigned short* w2t  = (unsigned short*)(ws + OFF_W2T);
    int* counts  = (int*)(ws + OFF_CNT);
    float* b1s   = (float*)(ws + OFF_B1S);
    float* b1q   = (float*)(ws + OFF_B1Q);
    float* b2s   = (float*)(ws + OFF_B2S);
    float* b2q   = (float*)(ws + OFF_B2Q);
    int* tex     = (int*)(ws + OFF_TEX);
    int* bsum    = (int*)(ws + OFF_BSUM);
    int* boff    = (int*)(ws + OFF_BOFF);
    int* Tptr    = (int*)(ws + OFF_T);
    int* cursor  = (int*)(ws + OFF_CUR);
    int* notile  = (int*)(ws + OFF_NOT);
    int* srcp    = (int*)(ws + OFF_SRCP);
    int* eidxp   = (int*)(ws + OFF_EIXP);
    float* sc1   = (float*)(ws + OFF_SC1);
    float* sb1   = (float*)(ws + OFF_SB1);
    float* sc2   = (float*)(ws + OFF_SC2);
    float* sb2   = (float*)(ws + OFF_SB2);

    hipMemsetAsync(aggr, 0, 102400000, stream);
    hipMemsetAsync(ws + OFF_CNT, 0, ZERO_BYTES, stream);
    hipMemsetAsync(srcp, 0xFF, (size_t)CAP_SLOT * 4, stream);
    k_convert<<<4224, 256, 0, stream>>>(W_e, W1, W2, wet, w1t, w2t);
    k_hist<<<(NE + 255) / 256, 256, 0, stream>>>(ei + NE, counts);
    k_scan1<<<NBLK_SCAN, 512, 0, stream>>>(counts, tex, bsum);
    k_scan2<<<1, 64, 0, stream>>>(bsum, boff, Tptr);
    k_scan3<<<NBLK_SCAN, 512, 0, stream>>>(counts, tex, boff, cursor, notile);
    k_scatter<<<(NE + 255) / 256, 256, 0, stream>>>(ei, ei + NE, cursor, srcp, eidxp);
    k_edge<<<CAP_TILE / 8, 512, 0, stream>>>(ea, wet, x, b_e, srcp, eidxp, notile, Tptr, aggr);
    k_combine<<<(int)(((long)NN * HD / 4 + 255) / 256), 256, 0, stream>>>(aggr, x, eps, h);
    k_gemm_bn<true, false><<<dim3((NN + 127) / 128, H2 / 128), 256, 0, stream>>>(
        h, w1t, b1, h1, b1s, b1q, nullptr, nullptr, NN, HD, H2);
    k_bn_final<<<4, 256, 0, stream>>>(b1s, b1q, g1, beta1, sc1, sb1, H2, 1.f / NN);
    k_gemm_bn<false, true><<<dim3((NN + 127) / 128, HD / 128), 256, 0, stream>>>(
        h1, w2t, b2, out, b2s, b2q, sc1, sb1, NN, H2, HD);
    k_bn_final<<<2, 256, 0, stream>>>(b2s, b2q, g2, beta2, sc2, sb2, HD, 1.f / NN);
    k_out<<<(int)(((long)NN * HD / 4 + 255) / 256), 256, 0, stream>>>(out, sc2, sb2, (long)NN * HD);
}